// Round 13
// baseline (422.970 us; speedup 1.0000x reference)
//
#include <hip/hip_runtime.h>

#define N_TOT 211072   // B*V = 32*6596
#define V_MESH 6596
#define E_TOT 633216   // 3*N
#define CAP 32
#define KD 264         // tileA/Wt row stride in bf16 (132 dwords)
#define KSTEPS 8       // K = 256 = [h(128) | S(128)]

typedef __attribute__((ext_vector_type(8))) short bf16x8;
typedef __attribute__((ext_vector_type(4))) float f32x4;

__constant__ float c_LIM[14] = {0.04f,0.06f,0.04f,0.04f,0.02f,0.02f,0.04f,0.04f,
                                0.03f,0.03f,0.02f,0.02f,0.01f,0.01f};

__device__ __forceinline__ unsigned f2bf(float f) {   // RNE f32->bf16
    unsigned x = __float_as_uint(f);
    return (x + 0x7fffu + ((x >> 16) & 1u)) >> 16;
}
__device__ __forceinline__ float bflo(unsigned u) { return __uint_as_float(u << 16); }
__device__ __forceinline__ float bfhi(unsigned u) { return __uint_as_float(u & 0xffff0000u); }
__device__ __forceinline__ unsigned cvt_pk_bf16(float lo, float hi) {
    unsigned r;
    asm("v_cvt_pk_bf16_f32 %0, %1, %2" : "=v"(r) : "v"(lo), "v"(hi));
    return r;
}

// ---------------- adjacency build (adj pre-initialized to -1 by memset 0xFF) ----------------
__global__ __launch_bounds__(256) void fill_adj_kernel(const int* __restrict__ edges,
                                                       int* __restrict__ cnt,
                                                       int* __restrict__ adj) {
    int e = blockIdx.x * 256 + threadIdx.x;
    if (e >= E_TOT) return;
    int2 ed = ((const int2*)edges)[e];
    int p0 = atomicAdd(&cnt[ed.x], 1);
    if (p0 < CAP) adj[(size_t)ed.x * CAP + p0] = ed.y;
    int p1 = atomicAdd(&cnt[ed.y], 1);
    if (p1 < CAP) adj[(size_t)ed.y * CAP + p1] = ed.x;
}

// ---------------- normals -> float4 rows (zero row lives at index -1) ----------------
__global__ __launch_bounds__(256) void prep_nrm4_kernel(const float* __restrict__ normals,
                                                        float4* __restrict__ nrm4) {
    int i = blockIdx.x * 256 + threadIdx.x;
    if (i >= N_TOT) return;
    float4 v;
    v.x = normals[(size_t)i * 3 + 0];
    v.y = normals[(size_t)i * 3 + 1];
    v.z = normals[(size_t)i * 3 + 2];
    v.w = 0.f;
    nrm4[i] = v;
}

// ---------------- neighbor-normal sums: SS[i] = (sum_j n_j, deg); sentinel -1 -> zero row ----
__global__ __launch_bounds__(256) void nsum_kernel(const float4* __restrict__ nrm4,
                                                   const int* __restrict__ cnt,
                                                   const int* __restrict__ adj,
                                                   float4* __restrict__ SS) {
    int i = blockIdx.x * 256 + threadIdx.x;
    if (i >= N_TOT) return;
    int deg = cnt[i]; if (deg > CAP) deg = CAP;
    const int4* a4 = (const int4*)(adj + (size_t)i * CAP);
    int4 A = a4[0], B = a4[1];
    float4 n0 = nrm4[A.x], n1 = nrm4[A.y], n2 = nrm4[A.z], n3 = nrm4[A.w];
    float4 m0 = nrm4[B.x], m1 = nrm4[B.y], m2 = nrm4[B.z], m3 = nrm4[B.w];
    float sx = ((n0.x + n1.x) + (n2.x + n3.x)) + ((m0.x + m1.x) + (m2.x + m3.x));
    float sy = ((n0.y + n1.y) + (n2.y + n3.y)) + ((m0.y + m1.y) + (m2.y + m3.y));
    float sz = ((n0.z + n1.z) + (n2.z + n3.z)) + ((m0.z + m1.z) + (m2.z + m3.z));
    for (int bq = 8; bq < deg; bq += 8) {
        int4 C = a4[bq / 4], D = a4[bq / 4 + 1];
        float4 p0 = nrm4[C.x], p1 = nrm4[C.y], p2 = nrm4[C.z], p3 = nrm4[C.w];
        float4 q0 = nrm4[D.x], q1 = nrm4[D.y], q2 = nrm4[D.z], q3 = nrm4[D.w];
        sx += ((p0.x + p1.x) + (p2.x + p3.x)) + ((q0.x + q1.x) + (q2.x + q3.x));
        sy += ((p0.y + p1.y) + (p2.y + p3.y)) + ((q0.y + q1.y) + (q2.y + q3.y));
        sz += ((p0.z + p1.z) + (p2.z + p3.z)) + ((q0.z + q1.z) + (q2.z + q3.z));
    }
    float4 out; out.x = sx; out.y = sy; out.z = sz; out.w = (float)deg;
    SS[i] = out;
}

// ---------------- weight conversion for fused layers ----------------
__global__ __launch_bounds__(256) void conv_w2_kernel(const float* __restrict__ w0,
                                                      const float* __restrict__ b0,
                                                      const float* __restrict__ w1,
                                                      const float* __restrict__ b1,
                                                      short* __restrict__ Wt,
                                                      float4* __restrict__ hdA,
                                                      float4* __restrict__ hdB) {
    int c = blockIdx.x;   // 0..127
    for (int k = threadIdx.x; k < KD; k += 256) {
        unsigned val = 0u;
        if (k < 128)      val = f2bf(w0[(size_t)k * 128 + c]);
        else if (k < 256) val = f2bf(w1[(size_t)(k - 128) * 128 + c]);
        Wt[(size_t)c * KD + k] = (short)val;
    }
    if (threadIdx.x == 0) {
        hdA[c] = make_float4(b0[c], b1[c], w0[128 * 128 + c], w0[129 * 128 + c]);
        hdB[c] = make_float4(w0[130 * 128 + c], w1[128 * 128 + c],
                             w1[129 * 128 + c], w1[130 * 128 + c]);
    }
}

// ---------------- layer 0: analytic h_1 (no gather, no GEMM) ----------------
__global__ __launch_bounds__(1024) void fused1_kernel(const float4* __restrict__ nrm4,
                                                      const float4* __restrict__ SS,
                                                      const float* __restrict__ w0,
                                                      const float* __restrict__ b0,
                                                      const float* __restrict__ w1,
                                                      const float* __restrict__ b1,
                                                      unsigned* __restrict__ hout) { // [N][64]
    __shared__ float wL[2][3][128];
    __shared__ float bL[2][128];
    int tid  = threadIdx.x;
    int w    = tid >> 6;
    int lane = tid & 63;
    int i    = blockIdx.x * 16 + w;

    if (tid < 768) {
        int mm = tid / 384, r = tid - mm * 384;
        (&wL[mm][0][0])[r] = (mm ? w1 : w0)[r];
    } else if (tid < 1024) {
        int t2 = tid - 768;
        if (t2 < 256) bL[t2 >> 7][t2 & 127] = ((t2 >> 7) ? b1 : b0)[t2 & 127];
    }
    float4 self4 = nrm4[i];
    float4 S4 = SS[i];
    float degf = S4.w;
    __syncthreads();

    int c0 = 2 * lane, c1 = 2 * lane + 1;
    float h0 = bL[0][c0] + degf * bL[1][c0]
             + self4.x * wL[0][0][c0] + self4.y * wL[0][1][c0] + self4.z * wL[0][2][c0]
             + S4.x * wL[1][0][c0] + S4.y * wL[1][1][c0] + S4.z * wL[1][2][c0];
    float h1 = bL[0][c1] + degf * bL[1][c1]
             + self4.x * wL[0][0][c1] + self4.y * wL[0][1][c1] + self4.z * wL[0][2][c1]
             + S4.x * wL[1][0][c1] + S4.y * wL[1][1][c1] + S4.z * wL[1][2][c1];
    hout[(size_t)i * 64 + lane] = cvt_pk_bf16(fmaxf(h0, 0.f), fmaxf(h1, 0.f));
}

// ---------------- fused layer (1,2): gather Sum(h) -> [h|S] GEMM + bias head -> h' ----------------
// 1024 threads = 16 waves, 32 rows/block; wave w owns nodes 2w, 2w+1 (16 gathers in flight).
// MFMA: wave w -> row half (w>>3), col block (w&7)*16. Sentinel j=-1 -> zero row at hin[-1].
template<int LAST>
__global__ __launch_bounds__(1024, 8) void fused2_kernel(const unsigned* __restrict__ hin, // [N][64], row -1 = 0
                                                         const float4* __restrict__ nrm4,
                                                         const float4* __restrict__ SS,
                                                         const int* __restrict__ cnt,
                                                         const int* __restrict__ adj,
                                                         const short* __restrict__ Wt,    // [128][KD]
                                                         const float4* __restrict__ hdA,
                                                         const float4* __restrict__ hdB,
                                                         unsigned* __restrict__ hnext,    // !LAST
                                                         const float* __restrict__ verts, // LAST...
                                                         const float* __restrict__ anchor_v,
                                                         const int* __restrict__ part_id,
                                                         const float* __restrict__ w_off,
                                                         const float* __restrict__ b_off,
                                                         float* __restrict__ houtf,
                                                         float* __restrict__ out_verts) {
    __shared__ short tileA[32 * KD];       // 16896 B: [h | S | pad]; LAST: reused as f32 staging
    __shared__ unsigned tileC[32 * 64];    // 8192 B (non-LAST staging)
    __shared__ float headL[32][8];         // n.xyz, deg, Sn.xyz
    __shared__ float woL[131 * 3];         // LAST
    __shared__ float partL[8][32][3];      // LAST

    int tid  = threadIdx.x;
    int w    = tid >> 6;      // 0..15
    int lane = tid & 63;
    int g    = lane >> 4;
    int ln   = lane & 15;
    int row0 = blockIdx.x * 32;
    int rA   = 2 * w, rB = 2 * w + 1;
    int iA   = row0 + rA, iB = row0 + rB;

    if (LAST) {
        for (int t = tid; t < 131 * 3; t += 1024) woL[t] = w_off[t];
    }

    // ---- adjacency (A in lanes 0..31, B in lanes 32..63) + self + head data ----
    int node = (lane < 32) ? iA : iB;
    int jv = adj[(size_t)node * CAP + (lane & 31)];
    int degA = cnt[iA]; degA = (degA > CAP) ? CAP : degA;
    int degB = cnt[iB]; degB = (degB > CAP) ? CAP : degB;
    unsigned selfA = hin[(size_t)iA * 64 + lane];
    unsigned selfB = hin[(size_t)iB * 64 + lane];
    float4 nn = nrm4[node];
    float4 sv = SS[node];
    if ((lane & 31) == 0) {
        int r = rA + (lane >> 5);
        headL[r][0] = nn.x; headL[r][1] = nn.y; headL[r][2] = nn.z; headL[r][3] = sv.w;
        headL[r][4] = sv.x; headL[r][5] = sv.y; headL[r][6] = sv.z; headL[r][7] = 0.f;
    }

    // ---- gather round 0: 8+8 unconditional loads in flight ----
    const unsigned* hb = hin + lane;
    unsigned uA[8], uB[8];
    #pragma unroll
    for (int q = 0; q < 8; ++q) {
        int jA = __builtin_amdgcn_readlane(jv, q);
        int jB = __builtin_amdgcn_readlane(jv, 32 + q);
        uA[q] = hb[(ptrdiff_t)jA * 64];
        uB[q] = hb[(ptrdiff_t)jB * 64];
    }
    float sA0 = 0.f, sA1 = 0.f, sB0 = 0.f, sB1 = 0.f;
    #pragma unroll
    for (int q = 0; q < 8; ++q) {
        sA0 += bflo(uA[q]); sA1 += bfhi(uA[q]);
        sB0 += bflo(uB[q]); sB1 += bfhi(uB[q]);
    }
    degA = __builtin_amdgcn_readfirstlane(degA);
    degB = __builtin_amdgcn_readfirstlane(degB);
    int degM = (degA > degB) ? degA : degB;
    for (int bq = 8; bq < degM; bq += 8) {
        unsigned vA[8], vB[8];
        #pragma unroll
        for (int q = 0; q < 8; ++q) {
            int jA = __builtin_amdgcn_readlane(jv, bq + q);
            int jB = __builtin_amdgcn_readlane(jv, 32 + bq + q);
            vA[q] = hb[(ptrdiff_t)jA * 64];
            vB[q] = hb[(ptrdiff_t)jB * 64];
        }
        #pragma unroll
        for (int q = 0; q < 8; ++q) {
            sA0 += bflo(vA[q]); sA1 += bfhi(vA[q]);
            sB0 += bflo(vB[q]); sB1 += bfhi(vB[q]);
        }
    }

    // ---- tileA rows: [self h (64 dw) | S (64 dw) | pad (4 dw)] ----
    unsigned* tA = (unsigned*)tileA;
    tA[rA * 132 + lane]      = selfA;
    tA[rB * 132 + lane]      = selfB;
    tA[rA * 132 + 64 + lane] = cvt_pk_bf16(sA0, sA1);
    tA[rB * 132 + 64 + lane] = cvt_pk_bf16(sB0, sB1);
    if (lane < 4) {
        tA[rA * 132 + 128 + lane] = 0u;
        tA[rB * 132 + 128 + lane] = 0u;
    }
    __syncthreads();

    // ---- MFMA: wave w -> row half rh, col block (w&7)*16, 16 rows, K=256 ----
    int rh = w >> 3;
    int cb = (w & 7) * 16, c = cb + ln;
    float4 hA = hdA[c], hB = hdB[c];
    bf16x8 bfrag[KSTEPS];
    #pragma unroll
    for (int kk = 0; kk < KSTEPS; ++kk)
        bfrag[kk] = *(const bf16x8*)(Wt + (size_t)c * KD + kk * 32 + g * 8);

    f32x4 acc;
    #pragma unroll
    for (int j = 0; j < 4; ++j) {
        int r = rh * 16 + g * 4 + j;
        acc[j] = hA.x + headL[r][3] * hA.y
               + headL[r][0] * hA.z + headL[r][1] * hA.w + headL[r][2] * hB.x
               + headL[r][4] * hB.y + headL[r][5] * hB.z + headL[r][6] * hB.w;
    }
    #pragma unroll
    for (int kk = 0; kk < KSTEPS; ++kk) {
        bf16x8 af = *(const bf16x8*)(tileA + (rh * 16 + ln) * KD + kk * 32 + g * 8);
        acc = __builtin_amdgcn_mfma_f32_16x16x32_bf16(af, bfrag[kk], acc, 0, 0, 0);
    }
    #pragma unroll
    for (int j = 0; j < 4; ++j) acc[j] = fmaxf(acc[j], 0.f);

    if (!LAST) {
        // pack pairs, swizzled store, coalesced writeback
        #pragma unroll
        for (int j = 0; j < 4; ++j) {
            float po = __shfl_xor(acc[j], 1);
            if (!(ln & 1)) {
                unsigned pk = cvt_pk_bf16(acc[j], po);
                int r = rh * 16 + g * 4 + j;
                int d = (cb + ln) >> 1;
                tileC[r * 64 + (d ^ ((r & 12) << 1))] = pk;
            }
        }
        __syncthreads();
        int r2 = 2 * w + (lane >> 5);
        int d2 = (lane & 31) * 2;
        int key = (r2 & 12) << 1;
        uint2 v2 = *(const uint2*)&tileC[r2 * 64 + (d2 ^ key)];
        *(uint2*)(hnext + (size_t)(row0 + r2) * 64 + d2) = v2;
    } else {
        // offset head partials (register-only)
        #pragma unroll
        for (int j = 0; j < 4; ++j) {
            int r = rh * 16 + g * 4 + j;
            float p0 = acc[j] * woL[c * 3 + 0];
            float p1 = acc[j] * woL[c * 3 + 1];
            float p2 = acc[j] * woL[c * 3 + 2];
            #pragma unroll
            for (int d = 1; d < 16; d <<= 1) {
                p0 += __shfl_xor(p0, d);
                p1 += __shfl_xor(p1, d);
                p2 += __shfl_xor(p2, d);
            }
            if (ln == 0) {
                partL[w & 7][r][0] = p0; partL[w & 7][r][1] = p1; partL[w & 7][r][2] = p2;
            }
        }
        __syncthreads();                       // everyone done reading tileA
        // stage h f32 in LDS (overlay tileA; stride 132 f32 -> 2-way banks)
        float* tCf = (float*)tileA;
        #pragma unroll
        for (int j = 0; j < 4; ++j) {
            int r = rh * 16 + g * 4 + j;
            tCf[r * 132 + c] = acc[j];
        }
        __syncthreads();
        // coalesced 512B row stores: thread tid -> row tid>>5, cols (tid&31)*4
        {
            int r = tid >> 5, c4 = (tid & 31) * 4;
            float4 v = *(const float4*)&tCf[r * 132 + c4];
            *(float4*)(houtf + (size_t)(row0 + r) * 128 + c4) = v;
        }
        if (tid < 96) {
            int r = tid / 3, t = tid - r * 3;
            int i = row0 + r;
            float s = 0.f;
            #pragma unroll
            for (int ww = 0; ww < 8; ++ww) s += partL[ww][r][t];
            s += headL[r][0] * woL[128 * 3 + t] + headL[r][1] * woL[129 * 3 + t]
               + headL[r][2] * woL[130 * 3 + t] + b_off[t];
            float dd = tanhf(s);
            int v = i % V_MESH;
            float lim = c_LIM[part_id[v]];
            dd = fminf(fmaxf(dd, -lim), lim);
            out_verts[(size_t)i * 3 + t] =
                verts[(size_t)i * 3 + t] + dd * anchor_v[(size_t)v * 3 + t];
        }
    }
}

extern "C" void kernel_launch(void* const* d_in, const int* in_sizes, int n_in,
                              void* d_out, int out_size, void* d_ws, size_t ws_size,
                              hipStream_t stream) {
    const float* verts    = (const float*)d_in[0];
    const float* normals  = (const float*)d_in[1];
    const float* anchor_v = (const float*)d_in[2];
    const int*   edges    = (const int*)d_in[3];
    const int*   part_id  = (const int*)d_in[4];
    const float* w0_0 = (const float*)d_in[5];
    const float* b0_0 = (const float*)d_in[6];
    const float* w1_0 = (const float*)d_in[7];
    const float* b1_0 = (const float*)d_in[8];
    const float* w0_1 = (const float*)d_in[9];
    const float* b0_1 = (const float*)d_in[10];
    const float* w1_1 = (const float*)d_in[11];
    const float* b1_1 = (const float*)d_in[12];
    const float* w0_2 = (const float*)d_in[13];
    const float* b0_2 = (const float*)d_in[14];
    const float* w1_2 = (const float*)d_in[15];
    const float* b1_2 = (const float*)d_in[16];
    const float* w_off = (const float*)d_in[17];
    const float* b_off = (const float*)d_in[18];

    float* out_verts = (float*)d_out;
    float* houtf = (float*)d_out + (size_t)3 * N_TOT;   // final h (f32)

    char* p = (char*)d_ws;
    unsigned* h1b = (unsigned*)p;  p += (size_t)(N_TOT + 1) * 64 * 4;  // zero row + h1
    unsigned* h2b = (unsigned*)p;  p += (size_t)(N_TOT + 1) * 64 * 4;  // zero row + h2
    int*    cnt  = (int*)p;        p += (size_t)N_TOT * 4;
    int*    adj  = (int*)p;        p += (size_t)N_TOT * CAP * 4;
    short*  Wt1  = (short*)p;      p += 128 * KD * 2;
    short*  Wt2  = (short*)p;      p += 128 * KD * 2;
    float4* hdA1 = (float4*)p;     p += 128 * 16;
    float4* hdB1 = (float4*)p;     p += 128 * 16;
    float4* hdA2 = (float4*)p;     p += 128 * 16;
    float4* hdB2 = (float4*)p;     p += 128 * 16;
    float4* nrm4b = (float4*)p;    p += (size_t)(N_TOT + 1) * 16;      // zero row + nrm4
    float4* SS   = (float4*)p;     p += (size_t)N_TOT * 16;

    unsigned* h1 = h1b + 64;          // row -1 = h1b
    unsigned* h2 = h2b + 64;
    float4* nrm4 = nrm4b + 1;         // row -1 = nrm4b[0]

    hipMemsetAsync(cnt, 0, (size_t)N_TOT * 4, stream);
    hipMemsetAsync(h1b, 0, 256, stream);                         // zero row h1
    hipMemsetAsync(h2b, 0, 256, stream);                         // zero row h2
    hipMemsetAsync(nrm4b, 0, 16, stream);                        // zero row nrm4
    hipMemsetAsync(adj, 0xFF, (size_t)N_TOT * CAP * 4, stream);  // sentinel -1
    fill_adj_kernel<<<(E_TOT + 255) / 256, 256, 0, stream>>>(edges, cnt, adj);
    prep_nrm4_kernel<<<(N_TOT + 255) / 256, 256, 0, stream>>>(normals, nrm4);
    conv_w2_kernel<<<128, 256, 0, stream>>>(w0_1, b0_1, w1_1, b1_1, Wt1, hdA1, hdB1);
    conv_w2_kernel<<<128, 256, 0, stream>>>(w0_2, b0_2, w1_2, b1_2, Wt2, hdA2, hdB2);
    nsum_kernel<<<(N_TOT + 255) / 256, 256, 0, stream>>>(nrm4, cnt, adj, SS);

    // layer 0: analytic -> h1
    fused1_kernel<<<N_TOT / 16, 1024, 0, stream>>>(nrm4, SS, w0_0, b0_0, w1_0, b1_0, h1);
    // layer 1: gather Sum(h1) -> GEMM -> h2
    fused2_kernel<0><<<N_TOT / 32, 1024, 0, stream>>>(h1, nrm4, SS, cnt, adj, Wt1, hdA1, hdB1,
                                                      h2, nullptr, nullptr, nullptr, nullptr,
                                                      nullptr, nullptr, nullptr);
    // layer 2 + epilogue: gather Sum(h2) -> GEMM -> h (f32) + verts
    fused2_kernel<1><<<N_TOT / 32, 1024, 0, stream>>>(h2, nrm4, SS, cnt, adj, Wt2, hdA2, hdB2,
                                                      nullptr, verts, anchor_v, part_id,
                                                      w_off, b_off, houtf, out_verts);
}

// Round 14
// 412.350 us; speedup vs baseline: 1.0258x; 1.0258x over previous
//
#include <hip/hip_runtime.h>

#define N_TOT 211072   // B*V = 32*6596
#define V_MESH 6596
#define E_TOT 633216   // 3*N
#define CAP 32
#define KD 264         // tileA/Wt row stride in bf16 (132 dwords)
#define KSTEPS 8       // K = 256 = [h(128) | S(128)]

typedef __attribute__((ext_vector_type(8))) short bf16x8;
typedef __attribute__((ext_vector_type(4))) float f32x4;

__constant__ float c_LIM[14] = {0.04f,0.06f,0.04f,0.04f,0.02f,0.02f,0.04f,0.04f,
                                0.03f,0.03f,0.02f,0.02f,0.01f,0.01f};

__device__ __forceinline__ unsigned f2bf(float f) {   // RNE f32->bf16
    unsigned x = __float_as_uint(f);
    return (x + 0x7fffu + ((x >> 16) & 1u)) >> 16;
}
__device__ __forceinline__ float bflo(unsigned u) { return __uint_as_float(u << 16); }
__device__ __forceinline__ float bfhi(unsigned u) { return __uint_as_float(u & 0xffff0000u); }
__device__ __forceinline__ unsigned cvt_pk_bf16(float lo, float hi) {
    unsigned r;
    asm("v_cvt_pk_bf16_f32 %0, %1, %2" : "=v"(r) : "v"(lo), "v"(hi));
    return r;
}

// ---------------- adjacency build (adj pre-initialized to -1 by memset 0xFF) ----------------
__global__ __launch_bounds__(256) void fill_adj_kernel(const int* __restrict__ edges,
                                                       int* __restrict__ cnt,
                                                       int* __restrict__ adj) {
    int e = blockIdx.x * 256 + threadIdx.x;
    if (e >= E_TOT) return;
    int2 ed = ((const int2*)edges)[e];
    int p0 = atomicAdd(&cnt[ed.x], 1);
    if (p0 < CAP) adj[(size_t)ed.x * CAP + p0] = ed.y;
    int p1 = atomicAdd(&cnt[ed.y], 1);
    if (p1 < CAP) adj[(size_t)ed.y * CAP + p1] = ed.x;
}

// ---------------- normals -> float4 rows (zero row lives at index -1) ----------------
__global__ __launch_bounds__(256) void prep_nrm4_kernel(const float* __restrict__ normals,
                                                        float4* __restrict__ nrm4) {
    int i = blockIdx.x * 256 + threadIdx.x;
    if (i >= N_TOT) return;
    float4 v;
    v.x = normals[(size_t)i * 3 + 0];
    v.y = normals[(size_t)i * 3 + 1];
    v.z = normals[(size_t)i * 3 + 2];
    v.w = 0.f;
    nrm4[i] = v;
}

// ---------------- neighbor-normal sums: SS[i] = (sum_j n_j, deg); sentinel -1 -> zero row ----
__global__ __launch_bounds__(256) void nsum_kernel(const float4* __restrict__ nrm4,
                                                   const int* __restrict__ cnt,
                                                   const int* __restrict__ adj,
                                                   float4* __restrict__ SS) {
    int i = blockIdx.x * 256 + threadIdx.x;
    if (i >= N_TOT) return;
    int deg = cnt[i]; if (deg > CAP) deg = CAP;
    const int4* a4 = (const int4*)(adj + (size_t)i * CAP);
    int4 A = a4[0], B = a4[1];
    float4 n0 = nrm4[A.x], n1 = nrm4[A.y], n2 = nrm4[A.z], n3 = nrm4[A.w];
    float4 m0 = nrm4[B.x], m1 = nrm4[B.y], m2 = nrm4[B.z], m3 = nrm4[B.w];
    float sx = ((n0.x + n1.x) + (n2.x + n3.x)) + ((m0.x + m1.x) + (m2.x + m3.x));
    float sy = ((n0.y + n1.y) + (n2.y + n3.y)) + ((m0.y + m1.y) + (m2.y + m3.y));
    float sz = ((n0.z + n1.z) + (n2.z + n3.z)) + ((m0.z + m1.z) + (m2.z + m3.z));
    for (int bq = 8; bq < deg; bq += 8) {
        int4 C = a4[bq / 4], D = a4[bq / 4 + 1];
        float4 p0 = nrm4[C.x], p1 = nrm4[C.y], p2 = nrm4[C.z], p3 = nrm4[C.w];
        float4 q0 = nrm4[D.x], q1 = nrm4[D.y], q2 = nrm4[D.z], q3 = nrm4[D.w];
        sx += ((p0.x + p1.x) + (p2.x + p3.x)) + ((q0.x + q1.x) + (q2.x + q3.x));
        sy += ((p0.y + p1.y) + (p2.y + p3.y)) + ((q0.y + q1.y) + (q2.y + q3.y));
        sz += ((p0.z + p1.z) + (p2.z + p3.z)) + ((q0.z + q1.z) + (q2.z + q3.z));
    }
    float4 out; out.x = sx; out.y = sy; out.z = sz; out.w = (float)deg;
    SS[i] = out;
}

// ---------------- weight conversion for fused layers ----------------
__global__ __launch_bounds__(256) void conv_w2_kernel(const float* __restrict__ w0,
                                                      const float* __restrict__ b0,
                                                      const float* __restrict__ w1,
                                                      const float* __restrict__ b1,
                                                      short* __restrict__ Wt,
                                                      float4* __restrict__ hdA,
                                                      float4* __restrict__ hdB) {
    int c = blockIdx.x;   // 0..127
    for (int k = threadIdx.x; k < KD; k += 256) {
        unsigned val = 0u;
        if (k < 128)      val = f2bf(w0[(size_t)k * 128 + c]);
        else if (k < 256) val = f2bf(w1[(size_t)(k - 128) * 128 + c]);
        Wt[(size_t)c * KD + k] = (short)val;
    }
    if (threadIdx.x == 0) {
        hdA[c] = make_float4(b0[c], b1[c], w0[128 * 128 + c], w0[129 * 128 + c]);
        hdB[c] = make_float4(w0[130 * 128 + c], w1[128 * 128 + c],
                             w1[129 * 128 + c], w1[130 * 128 + c]);
    }
}

// ---------------- layer 0: analytic h_1 (no gather, no GEMM) ----------------
__global__ __launch_bounds__(1024) void fused1_kernel(const float4* __restrict__ nrm4,
                                                      const float4* __restrict__ SS,
                                                      const float* __restrict__ w0,
                                                      const float* __restrict__ b0,
                                                      const float* __restrict__ w1,
                                                      const float* __restrict__ b1,
                                                      unsigned* __restrict__ hout) { // [N][64]
    __shared__ float wL[2][3][128];
    __shared__ float bL[2][128];
    int tid  = threadIdx.x;
    int w    = tid >> 6;
    int lane = tid & 63;
    int i    = blockIdx.x * 16 + w;

    if (tid < 768) {
        int mm = tid / 384, r = tid - mm * 384;
        (&wL[mm][0][0])[r] = (mm ? w1 : w0)[r];
    } else if (tid < 1024) {
        int t2 = tid - 768;
        if (t2 < 256) bL[t2 >> 7][t2 & 127] = ((t2 >> 7) ? b1 : b0)[t2 & 127];
    }
    float4 self4 = nrm4[i];
    float4 S4 = SS[i];
    float degf = S4.w;
    __syncthreads();

    int c0 = 2 * lane, c1 = 2 * lane + 1;
    float h0 = bL[0][c0] + degf * bL[1][c0]
             + self4.x * wL[0][0][c0] + self4.y * wL[0][1][c0] + self4.z * wL[0][2][c0]
             + S4.x * wL[1][0][c0] + S4.y * wL[1][1][c0] + S4.z * wL[1][2][c0];
    float h1 = bL[0][c1] + degf * bL[1][c1]
             + self4.x * wL[0][0][c1] + self4.y * wL[0][1][c1] + self4.z * wL[0][2][c1]
             + S4.x * wL[1][0][c1] + S4.y * wL[1][1][c1] + S4.z * wL[1][2][c1];
    hout[(size_t)i * 64 + lane] = cvt_pk_bf16(fmaxf(h0, 0.f), fmaxf(h1, 0.f));
}

// ---------------- fused layer (1,2): gather Sum(h) -> [h|S] GEMM + bias head -> h' ----------------
// 512 threads = 8 waves, 16 rows/block; wave w owns nodes 2w, 2w+1.
// 16-wide round 0: ALL 32 gathers (16 per node) issue before any waitcnt; sentinel -1 rows
// are L1-hit zeros. Tail loop only for deg>16 (P ~ 5e-5).
template<int LAST>
__global__ __launch_bounds__(512, 6) void fused2_kernel(const unsigned* __restrict__ hin, // [N][64], row -1 = 0
                                                        const float4* __restrict__ nrm4,
                                                        const float4* __restrict__ SS,
                                                        const int* __restrict__ cnt,
                                                        const int* __restrict__ adj,
                                                        const short* __restrict__ Wt,    // [128][KD]
                                                        const float4* __restrict__ hdA,
                                                        const float4* __restrict__ hdB,
                                                        unsigned* __restrict__ hnext,    // !LAST
                                                        const float* __restrict__ verts, // LAST...
                                                        const float* __restrict__ anchor_v,
                                                        const int* __restrict__ part_id,
                                                        const float* __restrict__ w_off,
                                                        const float* __restrict__ b_off,
                                                        float* __restrict__ houtf,
                                                        float* __restrict__ out_verts) {
    __shared__ short tileA[16 * KD];       // 8448 B: [h | S | pad]; LAST: reused as f32 staging
    __shared__ unsigned tileC[16 * 64];    // 4096 B (non-LAST staging)
    __shared__ float headL[16][8];         // n.xyz, deg, Sn.xyz
    __shared__ float woL[131 * 3];         // LAST
    __shared__ float partL[8][16][3];      // LAST

    int tid  = threadIdx.x;
    int w    = tid >> 6;
    int lane = tid & 63;
    int g    = lane >> 4;
    int ln   = lane & 15;
    int row0 = blockIdx.x * 16;
    int rA   = 2 * w, rB = 2 * w + 1;
    int iA   = row0 + rA, iB = row0 + rB;

    if (LAST) {
        for (int t = tid; t < 131 * 3; t += 512) woL[t] = w_off[t];
    }

    // ---- adjacency (A in lanes 0..31, B in lanes 32..63) + self + head data ----
    int node = (lane < 32) ? iA : iB;
    int jv = adj[(size_t)node * CAP + (lane & 31)];
    int degA = cnt[iA]; degA = (degA > CAP) ? CAP : degA;
    int degB = cnt[iB]; degB = (degB > CAP) ? CAP : degB;
    unsigned selfA = hin[(size_t)iA * 64 + lane];
    unsigned selfB = hin[(size_t)iB * 64 + lane];
    float4 nn = nrm4[node];
    float4 sv = SS[node];
    if ((lane & 31) == 0) {
        int r = rA + (lane >> 5);
        headL[r][0] = nn.x; headL[r][1] = nn.y; headL[r][2] = nn.z; headL[r][3] = sv.w;
        headL[r][4] = sv.x; headL[r][5] = sv.y; headL[r][6] = sv.z; headL[r][7] = 0.f;
    }

    // ---- 16-wide round 0: 32 unconditional loads, ALL in flight before any unpack ----
    const unsigned* hb = hin + lane;
    unsigned uA[16], uB[16];
    #pragma unroll
    for (int q = 0; q < 16; ++q) {
        int jA = __builtin_amdgcn_readlane(jv, q);
        uA[q] = hb[(ptrdiff_t)jA * 64];
    }
    #pragma unroll
    for (int q = 0; q < 16; ++q) {
        int jB = __builtin_amdgcn_readlane(jv, 32 + q);
        uB[q] = hb[(ptrdiff_t)jB * 64];
    }
    float sA0 = 0.f, sA1 = 0.f, sB0 = 0.f, sB1 = 0.f;
    #pragma unroll
    for (int q = 0; q < 16; ++q) { sA0 += bflo(uA[q]); sA1 += bfhi(uA[q]); }
    #pragma unroll
    for (int q = 0; q < 16; ++q) { sB0 += bflo(uB[q]); sB1 += bfhi(uB[q]); }

    // ---- rare tail: deg > 16 (P ~ 5e-5 per node) ----
    degA = __builtin_amdgcn_readfirstlane(degA);
    degB = __builtin_amdgcn_readfirstlane(degB);
    int degM = (degA > degB) ? degA : degB;
    for (int bq = 16; bq < degM; bq += 8) {
        unsigned vA[8], vB[8];
        #pragma unroll
        for (int q = 0; q < 8; ++q) {
            int jA = __builtin_amdgcn_readlane(jv, bq + q);
            int jB = __builtin_amdgcn_readlane(jv, 32 + bq + q);
            vA[q] = hb[(ptrdiff_t)jA * 64];
            vB[q] = hb[(ptrdiff_t)jB * 64];
        }
        #pragma unroll
        for (int q = 0; q < 8; ++q) {
            sA0 += bflo(vA[q]); sA1 += bfhi(vA[q]);
            sB0 += bflo(vB[q]); sB1 += bfhi(vB[q]);
        }
    }

    // ---- tileA rows: [self h (64 dw) | S (64 dw) | pad (4 dw)] ----
    unsigned* tA = (unsigned*)tileA;
    tA[rA * 132 + lane]      = selfA;
    tA[rB * 132 + lane]      = selfB;
    tA[rA * 132 + 64 + lane] = cvt_pk_bf16(sA0, sA1);
    tA[rB * 132 + 64 + lane] = cvt_pk_bf16(sB0, sB1);
    if (lane < 4) {
        tA[rA * 132 + 128 + lane] = 0u;
        tA[rB * 132 + 128 + lane] = 0u;
    }

    // ---- B fragments loaded here (overlap with barrier wait; u regs now dead) ----
    int cb = w * 16, c = cb + ln;
    bf16x8 bfrag[KSTEPS];
    #pragma unroll
    for (int kk = 0; kk < KSTEPS; ++kk)
        bfrag[kk] = *(const bf16x8*)(Wt + (size_t)c * KD + kk * 32 + g * 8);
    float4 hA = hdA[c], hB = hdB[c];
    __syncthreads();

    // ---- MFMA: wave w -> col block w*16, 16 rows, K=256 ----
    f32x4 acc;
    #pragma unroll
    for (int j = 0; j < 4; ++j) {
        int r = g * 4 + j;
        acc[j] = hA.x + headL[r][3] * hA.y
               + headL[r][0] * hA.z + headL[r][1] * hA.w + headL[r][2] * hB.x
               + headL[r][4] * hB.y + headL[r][5] * hB.z + headL[r][6] * hB.w;
    }
    #pragma unroll
    for (int kk = 0; kk < KSTEPS; ++kk) {
        bf16x8 af = *(const bf16x8*)(tileA + ln * KD + kk * 32 + g * 8);
        acc = __builtin_amdgcn_mfma_f32_16x16x32_bf16(af, bfrag[kk], acc, 0, 0, 0);
    }
    #pragma unroll
    for (int j = 0; j < 4; ++j) acc[j] = fmaxf(acc[j], 0.f);

    if (!LAST) {
        // pack pairs, swizzled store, coalesced writeback
        #pragma unroll
        for (int j = 0; j < 4; ++j) {
            float po = __shfl_xor(acc[j], 1);
            if (!(ln & 1)) {
                unsigned pk = cvt_pk_bf16(acc[j], po);
                int r = g * 4 + j;
                int d = (cb + ln) >> 1;
                tileC[r * 64 + (d ^ ((r & 12) << 1))] = pk;
            }
        }
        __syncthreads();
        int r2 = 2 * w + (lane >> 5);
        int d2 = (lane & 31) * 2;
        int key = (r2 & 12) << 1;
        uint2 v2 = *(const uint2*)&tileC[r2 * 64 + (d2 ^ key)];
        *(uint2*)(hnext + (size_t)(row0 + r2) * 64 + d2) = v2;
    } else {
        // offset head partials (register-only)
        #pragma unroll
        for (int j = 0; j < 4; ++j) {
            int r = g * 4 + j;
            float p0 = acc[j] * woL[c * 3 + 0];
            float p1 = acc[j] * woL[c * 3 + 1];
            float p2 = acc[j] * woL[c * 3 + 2];
            #pragma unroll
            for (int d = 1; d < 16; d <<= 1) {
                p0 += __shfl_xor(p0, d);
                p1 += __shfl_xor(p1, d);
                p2 += __shfl_xor(p2, d);
            }
            if (ln == 0) {
                partL[w][r][0] = p0; partL[w][r][1] = p1; partL[w][r][2] = p2;
            }
        }
        __syncthreads();                       // everyone done reading tileA
        // stage h f32 in LDS (overlay tileA; stride 132 f32 -> 2-way banks)
        float* tCf = (float*)tileA;
        #pragma unroll
        for (int j = 0; j < 4; ++j) {
            int r = g * 4 + j;
            tCf[r * 132 + c] = acc[j];
        }
        __syncthreads();
        // coalesced 512B row stores: thread tid -> row tid>>5, cols (tid&31)*4
        {
            int r = tid >> 5, c4 = (tid & 31) * 4;
            float4 v = *(const float4*)&tCf[r * 132 + c4];
            *(float4*)(houtf + (size_t)(row0 + r) * 128 + c4) = v;
        }
        if (tid < 48) {
            int r = tid / 3, t = tid - r * 3;
            int i = row0 + r;
            float s = 0.f;
            #pragma unroll
            for (int ww = 0; ww < 8; ++ww) s += partL[ww][r][t];
            s += headL[r][0] * woL[128 * 3 + t] + headL[r][1] * woL[129 * 3 + t]
               + headL[r][2] * woL[130 * 3 + t] + b_off[t];
            float dd = tanhf(s);
            int v = i % V_MESH;
            float lim = c_LIM[part_id[v]];
            dd = fminf(fmaxf(dd, -lim), lim);
            out_verts[(size_t)i * 3 + t] =
                verts[(size_t)i * 3 + t] + dd * anchor_v[(size_t)v * 3 + t];
        }
    }
}

extern "C" void kernel_launch(void* const* d_in, const int* in_sizes, int n_in,
                              void* d_out, int out_size, void* d_ws, size_t ws_size,
                              hipStream_t stream) {
    const float* verts    = (const float*)d_in[0];
    const float* normals  = (const float*)d_in[1];
    const float* anchor_v = (const float*)d_in[2];
    const int*   edges    = (const int*)d_in[3];
    const int*   part_id  = (const int*)d_in[4];
    const float* w0_0 = (const float*)d_in[5];
    const float* b0_0 = (const float*)d_in[6];
    const float* w1_0 = (const float*)d_in[7];
    const float* b1_0 = (const float*)d_in[8];
    const float* w0_1 = (const float*)d_in[9];
    const float* b0_1 = (const float*)d_in[10];
    const float* w1_1 = (const float*)d_in[11];
    const float* b1_1 = (const float*)d_in[12];
    const float* w0_2 = (const float*)d_in[13];
    const float* b0_2 = (const float*)d_in[14];
    const float* w1_2 = (const float*)d_in[15];
    const float* b1_2 = (const float*)d_in[16];
    const float* w_off = (const float*)d_in[17];
    const float* b_off = (const float*)d_in[18];

    float* out_verts = (float*)d_out;
    float* houtf = (float*)d_out + (size_t)3 * N_TOT;   // final h (f32)

    char* p = (char*)d_ws;
    unsigned* h1b = (unsigned*)p;  p += (size_t)(N_TOT + 1) * 64 * 4;  // zero row + h1
    unsigned* h2b = (unsigned*)p;  p += (size_t)(N_TOT + 1) * 64 * 4;  // zero row + h2
    int*    cnt  = (int*)p;        p += (size_t)N_TOT * 4;
    int*    adj  = (int*)p;        p += (size_t)N_TOT * CAP * 4;
    short*  Wt1  = (short*)p;      p += 128 * KD * 2;
    short*  Wt2  = (short*)p;      p += 128 * KD * 2;
    float4* hdA1 = (float4*)p;     p += 128 * 16;
    float4* hdB1 = (float4*)p;     p += 128 * 16;
    float4* hdA2 = (float4*)p;     p += 128 * 16;
    float4* hdB2 = (float4*)p;     p += 128 * 16;
    float4* nrm4b = (float4*)p;    p += (size_t)(N_TOT + 1) * 16;      // zero row + nrm4
    float4* SS   = (float4*)p;     p += (size_t)N_TOT * 16;

    unsigned* h1 = h1b + 64;          // row -1 = h1b
    unsigned* h2 = h2b + 64;
    float4* nrm4 = nrm4b + 1;         // row -1 = nrm4b[0]

    hipMemsetAsync(cnt, 0, (size_t)N_TOT * 4, stream);
    hipMemsetAsync(h1b, 0, 256, stream);                         // zero row h1
    hipMemsetAsync(h2b, 0, 256, stream);                         // zero row h2
    hipMemsetAsync(nrm4b, 0, 16, stream);                        // zero row nrm4
    hipMemsetAsync(adj, 0xFF, (size_t)N_TOT * CAP * 4, stream);  // sentinel -1
    fill_adj_kernel<<<(E_TOT + 255) / 256, 256, 0, stream>>>(edges, cnt, adj);
    prep_nrm4_kernel<<<(N_TOT + 255) / 256, 256, 0, stream>>>(normals, nrm4);
    conv_w2_kernel<<<128, 256, 0, stream>>>(w0_1, b0_1, w1_1, b1_1, Wt1, hdA1, hdB1);
    conv_w2_kernel<<<128, 256, 0, stream>>>(w0_2, b0_2, w1_2, b1_2, Wt2, hdA2, hdB2);
    nsum_kernel<<<(N_TOT + 255) / 256, 256, 0, stream>>>(nrm4, cnt, adj, SS);

    // layer 0: analytic -> h1
    fused1_kernel<<<N_TOT / 16, 1024, 0, stream>>>(nrm4, SS, w0_0, b0_0, w1_0, b1_0, h1);
    // layer 1: gather Sum(h1) -> GEMM -> h2
    fused2_kernel<0><<<N_TOT / 16, 512, 0, stream>>>(h1, nrm4, SS, cnt, adj, Wt1, hdA1, hdB1,
                                                     h2, nullptr, nullptr, nullptr, nullptr,
                                                     nullptr, nullptr, nullptr);
    // layer 2 + epilogue: gather Sum(h2) -> GEMM -> h (f32) + verts
    fused2_kernel<1><<<N_TOT / 16, 512, 0, stream>>>(h2, nrm4, SS, cnt, adj, Wt2, hdA2, hdB2,
                                                     nullptr, verts, anchor_v, part_id,
                                                     w_off, b_off, houtf, out_verts);
}

// Round 16
// 392.779 us; speedup vs baseline: 1.0769x; 1.0498x over previous
//
#include <hip/hip_runtime.h>

#define N_TOT 211072   // B*V = 32*6596
#define V_MESH 6596
#define E_TOT 633216   // 3*N
#define CAP 32
#define KD 264         // tileA/Wt row stride in bf16 (132 dwords)
#define KSTEPS 8       // K = 256 = [h(128) | S(128)]

typedef __attribute__((ext_vector_type(8))) short bf16x8;
typedef __attribute__((ext_vector_type(4))) float f32x4;
typedef __attribute__((ext_vector_type(2))) unsigned u32x2;

__constant__ float c_LIM[14] = {0.04f,0.06f,0.04f,0.04f,0.02f,0.02f,0.04f,0.04f,
                                0.03f,0.03f,0.02f,0.02f,0.01f,0.01f};

__device__ __forceinline__ unsigned f2bf(float f) {   // RNE f32->bf16
    unsigned x = __float_as_uint(f);
    return (x + 0x7fffu + ((x >> 16) & 1u)) >> 16;
}
__device__ __forceinline__ float bflo(unsigned u) { return __uint_as_float(u << 16); }
__device__ __forceinline__ float bfhi(unsigned u) { return __uint_as_float(u & 0xffff0000u); }
__device__ __forceinline__ unsigned cvt_pk_bf16(float lo, float hi) {
    unsigned r;
    asm("v_cvt_pk_bf16_f32 %0, %1, %2" : "=v"(r) : "v"(lo), "v"(hi));
    return r;
}

// ---------------- ONE init kernel: cnt=0, adj=-1, zero rows, nrm4 prep, weight conv x2 ----
__global__ __launch_bounds__(256) void init_kernel(const float* __restrict__ normals,
                                                   const float* __restrict__ w0_1,
                                                   const float* __restrict__ b0_1,
                                                   const float* __restrict__ w1_1,
                                                   const float* __restrict__ b1_1,
                                                   const float* __restrict__ w0_2,
                                                   const float* __restrict__ b0_2,
                                                   const float* __restrict__ w1_2,
                                                   const float* __restrict__ b1_2,
                                                   int* __restrict__ cnt,
                                                   int4* __restrict__ adj4,
                                                   unsigned* __restrict__ h1b,
                                                   unsigned* __restrict__ h2b,
                                                   float4* __restrict__ nrm4b,
                                                   short* __restrict__ Wt1,
                                                   float4* __restrict__ hdA1,
                                                   float4* __restrict__ hdB1,
                                                   short* __restrict__ Wt2,
                                                   float4* __restrict__ hdA2,
                                                   float4* __restrict__ hdB2) {
    unsigned idx = blockIdx.x * 256 + threadIdx.x;
    if (idx < (unsigned)(N_TOT * CAP / 4)) adj4[idx] = make_int4(-1, -1, -1, -1);
    if (idx < (unsigned)N_TOT) {
        cnt[idx] = 0;
        float4 v;
        v.x = normals[(size_t)idx * 3 + 0];
        v.y = normals[(size_t)idx * 3 + 1];
        v.z = normals[(size_t)idx * 3 + 2];
        v.w = 0.f;
        nrm4b[idx + 1] = v;
    }
    if (idx == 0) nrm4b[0] = make_float4(0.f, 0.f, 0.f, 0.f);
    if (idx < 64) { h1b[idx] = 0u; h2b[idx] = 0u; }
    if (idx < (unsigned)(128 * KD)) {
        int c = idx / KD, k = idx - c * KD;
        unsigned v1 = 0u, v2 = 0u;
        if (k < 128)      { v1 = f2bf(w0_1[(size_t)k * 128 + c]);        v2 = f2bf(w0_2[(size_t)k * 128 + c]); }
        else if (k < 256) { v1 = f2bf(w1_1[(size_t)(k - 128) * 128 + c]); v2 = f2bf(w1_2[(size_t)(k - 128) * 128 + c]); }
        Wt1[idx] = (short)v1;
        Wt2[idx] = (short)v2;
    }
    if (idx < 128) {
        int c = idx;
        hdA1[c] = make_float4(b0_1[c], b1_1[c], w0_1[128*128 + c], w0_1[129*128 + c]);
        hdB1[c] = make_float4(w0_1[130*128 + c], w1_1[128*128 + c], w1_1[129*128 + c], w1_1[130*128 + c]);
        hdA2[c] = make_float4(b0_2[c], b1_2[c], w0_2[128*128 + c], w0_2[129*128 + c]);
        hdB2[c] = make_float4(w0_2[130*128 + c], w1_2[128*128 + c], w1_2[129*128 + c], w1_2[130*128 + c]);
    }
}

// ---------------- adjacency build (adj pre-initialized to -1) ----------------
__global__ __launch_bounds__(256) void fill_adj_kernel(const int* __restrict__ edges,
                                                       int* __restrict__ cnt,
                                                       int* __restrict__ adj) {
    int e = blockIdx.x * 256 + threadIdx.x;
    if (e >= E_TOT) return;
    int2 ed = ((const int2*)edges)[e];
    int p0 = atomicAdd(&cnt[ed.x], 1);
    if (p0 < CAP) adj[(size_t)ed.x * CAP + p0] = ed.y;
    int p1 = atomicAdd(&cnt[ed.y], 1);
    if (p1 < CAP) adj[(size_t)ed.y * CAP + p1] = ed.x;
}

// ---------------- neighbor-normal sums: SS[i] = (sum_j n_j, deg); sentinel -1 -> zero row ----
__global__ __launch_bounds__(256) void nsum_kernel(const float4* __restrict__ nrm4,
                                                   const int* __restrict__ cnt,
                                                   const int* __restrict__ adj,
                                                   float4* __restrict__ SS) {
    int i = blockIdx.x * 256 + threadIdx.x;
    if (i >= N_TOT) return;
    int deg = cnt[i]; if (deg > CAP) deg = CAP;
    const int4* a4 = (const int4*)(adj + (size_t)i * CAP);
    int4 A = a4[0], B = a4[1];
    float4 n0 = nrm4[A.x], n1 = nrm4[A.y], n2 = nrm4[A.z], n3 = nrm4[A.w];
    float4 m0 = nrm4[B.x], m1 = nrm4[B.y], m2 = nrm4[B.z], m3 = nrm4[B.w];
    float sx = ((n0.x + n1.x) + (n2.x + n3.x)) + ((m0.x + m1.x) + (m2.x + m3.x));
    float sy = ((n0.y + n1.y) + (n2.y + n3.y)) + ((m0.y + m1.y) + (m2.y + m3.y));
    float sz = ((n0.z + n1.z) + (n2.z + n3.z)) + ((m0.z + m1.z) + (m2.z + m3.z));
    for (int bq = 8; bq < deg; bq += 8) {
        int4 C = a4[bq / 4], D = a4[bq / 4 + 1];
        float4 p0 = nrm4[C.x], p1 = nrm4[C.y], p2 = nrm4[C.z], p3 = nrm4[C.w];
        float4 q0 = nrm4[D.x], q1 = nrm4[D.y], q2 = nrm4[D.z], q3 = nrm4[D.w];
        sx += ((p0.x + p1.x) + (p2.x + p3.x)) + ((q0.x + q1.x) + (q2.x + q3.x));
        sy += ((p0.y + p1.y) + (p2.y + p3.y)) + ((q0.y + q1.y) + (q2.y + q3.y));
        sz += ((p0.z + p1.z) + (p2.z + p3.z)) + ((q0.z + q1.z) + (q2.z + q3.z));
    }
    float4 out; out.x = sx; out.y = sy; out.z = sz; out.w = (float)deg;
    SS[i] = out;
}

// ---------------- layer 0: analytic h_1 (no gather, no GEMM) ----------------
__global__ __launch_bounds__(1024) void fused1_kernel(const float4* __restrict__ nrm4,
                                                      const float4* __restrict__ SS,
                                                      const float* __restrict__ w0,
                                                      const float* __restrict__ b0,
                                                      const float* __restrict__ w1,
                                                      const float* __restrict__ b1,
                                                      unsigned* __restrict__ hout) { // [N][64]
    __shared__ float wL[2][3][128];
    __shared__ float bL[2][128];
    int tid  = threadIdx.x;
    int w    = tid >> 6;
    int lane = tid & 63;
    int i    = blockIdx.x * 16 + w;

    if (tid < 768) {
        int mm = tid / 384, r = tid - mm * 384;
        (&wL[mm][0][0])[r] = (mm ? w1 : w0)[r];
    } else if (tid < 1024) {
        int t2 = tid - 768;
        if (t2 < 256) bL[t2 >> 7][t2 & 127] = ((t2 >> 7) ? b1 : b0)[t2 & 127];
    }
    float4 self4 = nrm4[i];
    float4 S4 = SS[i];
    float degf = S4.w;
    __syncthreads();

    int c0 = 2 * lane, c1 = 2 * lane + 1;
    float h0 = bL[0][c0] + degf * bL[1][c0]
             + self4.x * wL[0][0][c0] + self4.y * wL[0][1][c0] + self4.z * wL[0][2][c0]
             + S4.x * wL[1][0][c0] + S4.y * wL[1][1][c0] + S4.z * wL[1][2][c0];
    float h1 = bL[0][c1] + degf * bL[1][c1]
             + self4.x * wL[0][0][c1] + self4.y * wL[0][1][c1] + self4.z * wL[0][2][c1]
             + S4.x * wL[1][0][c1] + S4.y * wL[1][1][c1] + S4.z * wL[1][2][c1];
    hout[(size_t)i * 64 + lane] = cvt_pk_bf16(fmaxf(h0, 0.f), fmaxf(h1, 0.f));
}

// ---------------- fused layer (1,2): gather Sum(h) -> [h|S] GEMM + bias head -> h' ----------------
// r12-optimal structure: 512 threads = 8 waves, 16 rows/block; wave w owns nodes 2w, 2w+1.
// 8-wide round 0, A/B tail rounds in parallel to max(degA,degB). deg comes from SS.w (no cnt load).
template<int LAST>
__global__ __launch_bounds__(512, 8) void fused2_kernel(const unsigned* __restrict__ hin, // [N][64], row -1 = 0
                                                        const float4* __restrict__ nrm4,
                                                        const float4* __restrict__ SS,
                                                        const int* __restrict__ adj,
                                                        const short* __restrict__ Wt,    // [128][KD]
                                                        const float4* __restrict__ hdA,
                                                        const float4* __restrict__ hdB,
                                                        unsigned* __restrict__ hnext,    // !LAST
                                                        const float* __restrict__ verts, // LAST...
                                                        const float* __restrict__ anchor_v,
                                                        const int* __restrict__ part_id,
                                                        const float* __restrict__ w_off,
                                                        const float* __restrict__ b_off,
                                                        float* __restrict__ houtf,
                                                        float* __restrict__ out_verts) {
    __shared__ short tileA[16 * KD];       // 8448 B: [h | S | pad]; LAST: reused as f32 staging
    __shared__ unsigned tileC[16 * 64];    // 4096 B (non-LAST staging)
    __shared__ float headL[16][8];         // n.xyz, deg, Sn.xyz
    __shared__ float woL[131 * 3];         // LAST
    __shared__ float partL[8][16][3];      // LAST

    int tid  = threadIdx.x;
    int w    = tid >> 6;
    int lane = tid & 63;
    int g    = lane >> 4;
    int ln   = lane & 15;
    int row0 = blockIdx.x * 16;
    int rA   = 2 * w, rB = 2 * w + 1;
    int iA   = row0 + rA, iB = row0 + rB;

    if (LAST) {
        for (int t = tid; t < 131 * 3; t += 512) woL[t] = w_off[t];
    }

    // ---- adjacency (A in lanes 0..31, B in lanes 32..63) + self + head data ----
    int node = (lane < 32) ? iA : iB;
    int jv = adj[(size_t)node * CAP + (lane & 31)];
    unsigned selfA = hin[(size_t)iA * 64 + lane];
    unsigned selfB = hin[(size_t)iB * 64 + lane];
    float4 nn = nrm4[node];
    float4 sv = SS[node];
    int degl = (int)sv.w;
    if ((lane & 31) == 0) {
        int r = rA + (lane >> 5);
        headL[r][0] = nn.x; headL[r][1] = nn.y; headL[r][2] = nn.z; headL[r][3] = sv.w;
        headL[r][4] = sv.x; headL[r][5] = sv.y; headL[r][6] = sv.z; headL[r][7] = 0.f;
    }

    // ---- gather round 0: 8+8 unconditional loads in flight ----
    const unsigned* hb = hin + lane;
    unsigned uA[8], uB[8];
    #pragma unroll
    for (int q = 0; q < 8; ++q) {
        int jA = __builtin_amdgcn_readlane(jv, q);
        int jB = __builtin_amdgcn_readlane(jv, 32 + q);
        uA[q] = hb[(ptrdiff_t)jA * 64];
        uB[q] = hb[(ptrdiff_t)jB * 64];
    }
    float sA0 = 0.f, sA1 = 0.f, sB0 = 0.f, sB1 = 0.f;
    #pragma unroll
    for (int q = 0; q < 8; ++q) {
        sA0 += bflo(uA[q]); sA1 += bfhi(uA[q]);
        sB0 += bflo(uB[q]); sB1 += bfhi(uB[q]);
    }
    int degA = __builtin_amdgcn_readlane(degl, 0);
    int degB = __builtin_amdgcn_readlane(degl, 32);
    int degM = (degA > degB) ? degA : degB;
    // ---- extra rounds: A and B issued together (sentinel-padded, branch-free bodies) ----
    for (int bq = 8; bq < degM; bq += 8) {
        unsigned vA[8], vB[8];
        #pragma unroll
        for (int q = 0; q < 8; ++q) {
            int jA = __builtin_amdgcn_readlane(jv, bq + q);
            int jB = __builtin_amdgcn_readlane(jv, 32 + bq + q);
            vA[q] = hb[(ptrdiff_t)jA * 64];
            vB[q] = hb[(ptrdiff_t)jB * 64];
        }
        #pragma unroll
        for (int q = 0; q < 8; ++q) {
            sA0 += bflo(vA[q]); sA1 += bfhi(vA[q]);
            sB0 += bflo(vB[q]); sB1 += bfhi(vB[q]);
        }
    }

    // ---- tileA rows: [self h (64 dw) | S (64 dw) | pad (4 dw)] ----
    unsigned* tA = (unsigned*)tileA;
    tA[rA * 132 + lane]      = selfA;
    tA[rB * 132 + lane]      = selfB;
    tA[rA * 132 + 64 + lane] = cvt_pk_bf16(sA0, sA1);
    tA[rB * 132 + 64 + lane] = cvt_pk_bf16(sB0, sB1);
    if (lane < 4) {
        tA[rA * 132 + 128 + lane] = 0u;
        tA[rB * 132 + 128 + lane] = 0u;
    }
    __syncthreads();

    // ---- MFMA: wave w -> col block w*16, 16 rows, K=256 ----
    int cb = w * 16, c = cb + ln;
    float4 hA = hdA[c], hB = hdB[c];
    bf16x8 bfrag[KSTEPS];
    #pragma unroll
    for (int kk = 0; kk < KSTEPS; ++kk)
        bfrag[kk] = *(const bf16x8*)(Wt + (size_t)c * KD + kk * 32 + g * 8);

    f32x4 acc;
    #pragma unroll
    for (int j = 0; j < 4; ++j) {
        int r = g * 4 + j;
        acc[j] = hA.x + headL[r][3] * hA.y
               + headL[r][0] * hA.z + headL[r][1] * hA.w + headL[r][2] * hB.x
               + headL[r][4] * hB.y + headL[r][5] * hB.z + headL[r][6] * hB.w;
    }
    #pragma unroll
    for (int kk = 0; kk < KSTEPS; ++kk) {
        bf16x8 af = *(const bf16x8*)(tileA + ln * KD + kk * 32 + g * 8);
        acc = __builtin_amdgcn_mfma_f32_16x16x32_bf16(af, bfrag[kk], acc, 0, 0, 0);
    }
    #pragma unroll
    for (int j = 0; j < 4; ++j) acc[j] = fmaxf(acc[j], 0.f);

    if (!LAST) {
        // pack pairs, swizzled store, coalesced nontemporal writeback
        #pragma unroll
        for (int j = 0; j < 4; ++j) {
            float po = __shfl_xor(acc[j], 1);
            if (!(ln & 1)) {
                unsigned pk = cvt_pk_bf16(acc[j], po);
                int r = g * 4 + j;
                int d = (cb + ln) >> 1;
                tileC[r * 64 + (d ^ ((r & 12) << 1))] = pk;
            }
        }
        __syncthreads();
        int r2 = 2 * w + (lane >> 5);
        int d2 = (lane & 31) * 2;
        int key = (r2 & 12) << 1;
        u32x2 v2 = *(const u32x2*)&tileC[r2 * 64 + (d2 ^ key)];
        __builtin_nontemporal_store(v2, (u32x2*)(hnext + (size_t)(row0 + r2) * 64 + d2));
    } else {
        // offset head partials (register-only)
        #pragma unroll
        for (int j = 0; j < 4; ++j) {
            int r = g * 4 + j;
            float p0 = acc[j] * woL[c * 3 + 0];
            float p1 = acc[j] * woL[c * 3 + 1];
            float p2 = acc[j] * woL[c * 3 + 2];
            #pragma unroll
            for (int d = 1; d < 16; d <<= 1) {
                p0 += __shfl_xor(p0, d);
                p1 += __shfl_xor(p1, d);
                p2 += __shfl_xor(p2, d);
            }
            if (ln == 0) {
                partL[w][r][0] = p0; partL[w][r][1] = p1; partL[w][r][2] = p2;
            }
        }
        __syncthreads();                       // everyone done reading tileA
        // stage h f32 in LDS (overlay tileA; stride 132 f32 -> 2-way banks)
        float* tCf = (float*)tileA;
        #pragma unroll
        for (int j = 0; j < 4; ++j) {
            int r = g * 4 + j;
            tCf[r * 132 + c] = acc[j];
        }
        __syncthreads();
        // coalesced 512B nontemporal row stores
        {
            int r = tid >> 5, c4 = (tid & 31) * 4;
            f32x4 v = *(const f32x4*)&tCf[r * 132 + c4];
            __builtin_nontemporal_store(v, (f32x4*)(houtf + (size_t)(row0 + r) * 128 + c4));
        }
        if (tid < 48) {
            int r = tid / 3, t = tid - r * 3;
            int i = row0 + r;
            float s = 0.f;
            #pragma unroll
            for (int ww = 0; ww < 8; ++ww) s += partL[ww][r][t];
            s += headL[r][0] * woL[128 * 3 + t] + headL[r][1] * woL[129 * 3 + t]
               + headL[r][2] * woL[130 * 3 + t] + b_off[t];
            float dd = tanhf(s);
            int v = i % V_MESH;
            float lim = c_LIM[part_id[v]];
            dd = fminf(fmaxf(dd, -lim), lim);
            out_verts[(size_t)i * 3 + t] =
                verts[(size_t)i * 3 + t] + dd * anchor_v[(size_t)v * 3 + t];
        }
    }
}

extern "C" void kernel_launch(void* const* d_in, const int* in_sizes, int n_in,
                              void* d_out, int out_size, void* d_ws, size_t ws_size,
                              hipStream_t stream) {
    const float* verts    = (const float*)d_in[0];
    const float* normals  = (const float*)d_in[1];
    const float* anchor_v = (const float*)d_in[2];
    const int*   edges    = (const int*)d_in[3];
    const int*   part_id  = (const int*)d_in[4];
    const float* w0_0 = (const float*)d_in[5];
    const float* b0_0 = (const float*)d_in[6];
    const float* w1_0 = (const float*)d_in[7];
    const float* b1_0 = (const float*)d_in[8];
    const float* w0_1 = (const float*)d_in[9];
    const float* b0_1 = (const float*)d_in[10];
    const float* w1_1 = (const float*)d_in[11];
    const float* b1_1 = (const float*)d_in[12];
    const float* w0_2 = (const float*)d_in[13];
    const float* b0_2 = (const float*)d_in[14];
    const float* w1_2 = (const float*)d_in[15];
    const float* b1_2 = (const float*)d_in[16];
    const float* w_off = (const float*)d_in[17];
    const float* b_off = (const float*)d_in[18];

    float* out_verts = (float*)d_out;
    float* houtf = (float*)d_out + (size_t)3 * N_TOT;   // final h (f32)

    char* p = (char*)d_ws;
    unsigned* h1b = (unsigned*)p;  p += (size_t)(N_TOT + 1) * 64 * 4;  // zero row + h1
    unsigned* h2b = (unsigned*)p;  p += (size_t)(N_TOT + 1) * 64 * 4;  // zero row + h2
    int*    cnt  = (int*)p;        p += (size_t)N_TOT * 4;
    int*    adj  = (int*)p;        p += (size_t)N_TOT * CAP * 4;
    short*  Wt1  = (short*)p;      p += 128 * KD * 2;
    short*  Wt2  = (short*)p;      p += 128 * KD * 2;
    float4* hdA1 = (float4*)p;     p += 128 * 16;
    float4* hdB1 = (float4*)p;     p += 128 * 16;
    float4* hdA2 = (float4*)p;     p += 128 * 16;
    float4* hdB2 = (float4*)p;     p += 128 * 16;
    float4* nrm4b = (float4*)p;    p += (size_t)(N_TOT + 1) * 16;      // zero row + nrm4
    float4* SS   = (float4*)p;     p += (size_t)N_TOT * 16;

    unsigned* h1 = h1b + 64;          // row -1 = h1b
    unsigned* h2 = h2b + 64;
    float4* nrm4 = nrm4b + 1;         // row -1 = nrm4b[0]

    // one init kernel replaces 5 memsets + prep + 2 weight-conv dispatches
    init_kernel<<<(N_TOT * CAP / 4 + 255) / 256, 256, 0, stream>>>(
        normals, w0_1, b0_1, w1_1, b1_1, w0_2, b0_2, w1_2, b1_2,
        cnt, (int4*)adj, h1b, h2b, nrm4b, Wt1, hdA1, hdB1, Wt2, hdA2, hdB2);
    fill_adj_kernel<<<(E_TOT + 255) / 256, 256, 0, stream>>>(edges, cnt, adj);
    nsum_kernel<<<(N_TOT + 255) / 256, 256, 0, stream>>>(nrm4, cnt, adj, SS);

    // layer 0: analytic -> h1
    fused1_kernel<<<N_TOT / 16, 1024, 0, stream>>>(nrm4, SS, w0_0, b0_0, w1_0, b1_0, h1);
    // layer 1: gather Sum(h1) -> GEMM -> h2
    fused2_kernel<0><<<N_TOT / 16, 512, 0, stream>>>(h1, nrm4, SS, adj, Wt1, hdA1, hdB1,
                                                     h2, nullptr, nullptr, nullptr, nullptr,
                                                     nullptr, nullptr, nullptr);
    // layer 2 + epilogue: gather Sum(h2) -> GEMM -> h (f32) + verts
    fused2_kernel<1><<<N_TOT / 16, 512, 0, stream>>>(h2, nrm4, SS, adj, Wt2, hdA2, hdB2,
                                                     nullptr, verts, anchor_v, part_id,
                                                     w_off, b_off, houtf, out_verts);
}

// Round 17
// 387.261 us; speedup vs baseline: 1.0922x; 1.0142x over previous
//
#include <hip/hip_runtime.h>

#define N_TOT 211072   // B*V = 32*6596
#define V_MESH 6596
#define E_TOT 633216   // 3*N
#define CAP 32
#define KD 264         // tileA/Wt row stride in bf16 (132 dwords)
#define KSTEPS 8       // K = 256 = [h(128) | S(128)]

typedef __attribute__((ext_vector_type(8))) short bf16x8;
typedef __attribute__((ext_vector_type(4))) float f32x4;

__constant__ float c_LIM[14] = {0.04f,0.06f,0.04f,0.04f,0.02f,0.02f,0.04f,0.04f,
                                0.03f,0.03f,0.02f,0.02f,0.01f,0.01f};

__device__ __forceinline__ unsigned f2bf(float f) {   // RNE f32->bf16
    unsigned x = __float_as_uint(f);
    return (x + 0x7fffu + ((x >> 16) & 1u)) >> 16;
}
__device__ __forceinline__ float bflo(unsigned u) { return __uint_as_float(u << 16); }
__device__ __forceinline__ float bfhi(unsigned u) { return __uint_as_float(u & 0xffff0000u); }
__device__ __forceinline__ unsigned cvt_pk_bf16(float lo, float hi) {
    unsigned r;
    asm("v_cvt_pk_bf16_f32 %0, %1, %2" : "=v"(r) : "v"(lo), "v"(hi));
    return r;
}

// ---------------- ONE init kernel: cnt=0, adj=-1, zero rows, nrm4 prep, weight conv x2 ----
__global__ __launch_bounds__(256) void init_kernel(const float* __restrict__ normals,
                                                   const float* __restrict__ w0_1,
                                                   const float* __restrict__ b0_1,
                                                   const float* __restrict__ w1_1,
                                                   const float* __restrict__ b1_1,
                                                   const float* __restrict__ w0_2,
                                                   const float* __restrict__ b0_2,
                                                   const float* __restrict__ w1_2,
                                                   const float* __restrict__ b1_2,
                                                   int* __restrict__ cnt,
                                                   int4* __restrict__ adj4,
                                                   unsigned* __restrict__ h1b,
                                                   unsigned* __restrict__ h2b,
                                                   float4* __restrict__ nrm4b,
                                                   short* __restrict__ Wt1,
                                                   float4* __restrict__ hdA1,
                                                   float4* __restrict__ hdB1,
                                                   short* __restrict__ Wt2,
                                                   float4* __restrict__ hdA2,
                                                   float4* __restrict__ hdB2) {
    unsigned idx = blockIdx.x * 256 + threadIdx.x;
    if (idx < (unsigned)(N_TOT * CAP / 4)) adj4[idx] = make_int4(-1, -1, -1, -1);
    if (idx < (unsigned)N_TOT) {
        cnt[idx] = 0;
        float4 v;
        v.x = normals[(size_t)idx * 3 + 0];
        v.y = normals[(size_t)idx * 3 + 1];
        v.z = normals[(size_t)idx * 3 + 2];
        v.w = 0.f;
        nrm4b[idx + 1] = v;
    }
    if (idx == 0) nrm4b[0] = make_float4(0.f, 0.f, 0.f, 0.f);
    if (idx < 64) { h1b[idx] = 0u; h2b[idx] = 0u; }
    if (idx < (unsigned)(128 * KD)) {
        int c = idx / KD, k = idx - c * KD;
        unsigned v1 = 0u, v2 = 0u;
        if (k < 128)      { v1 = f2bf(w0_1[(size_t)k * 128 + c]);        v2 = f2bf(w0_2[(size_t)k * 128 + c]); }
        else if (k < 256) { v1 = f2bf(w1_1[(size_t)(k - 128) * 128 + c]); v2 = f2bf(w1_2[(size_t)(k - 128) * 128 + c]); }
        Wt1[idx] = (short)v1;
        Wt2[idx] = (short)v2;
    }
    if (idx < 128) {
        int c = idx;
        hdA1[c] = make_float4(b0_1[c], b1_1[c], w0_1[128*128 + c], w0_1[129*128 + c]);
        hdB1[c] = make_float4(w0_1[130*128 + c], w1_1[128*128 + c], w1_1[129*128 + c], w1_1[130*128 + c]);
        hdA2[c] = make_float4(b0_2[c], b1_2[c], w0_2[128*128 + c], w0_2[129*128 + c]);
        hdB2[c] = make_float4(w0_2[130*128 + c], w1_2[128*128 + c], w1_2[129*128 + c], w1_2[130*128 + c]);
    }
}

// ---------------- adjacency build (adj pre-initialized to -1) ----------------
__global__ __launch_bounds__(256) void fill_adj_kernel(const int* __restrict__ edges,
                                                       int* __restrict__ cnt,
                                                       int* __restrict__ adj) {
    int e = blockIdx.x * 256 + threadIdx.x;
    if (e >= E_TOT) return;
    int2 ed = ((const int2*)edges)[e];
    int p0 = atomicAdd(&cnt[ed.x], 1);
    if (p0 < CAP) adj[(size_t)ed.x * CAP + p0] = ed.y;
    int p1 = atomicAdd(&cnt[ed.y], 1);
    if (p1 < CAP) adj[(size_t)ed.y * CAP + p1] = ed.x;
}

// ---------------- neighbor-normal sums: SS[i] = (sum_j n_j, deg); sentinel -1 -> zero row ----
__global__ __launch_bounds__(256) void nsum_kernel(const float4* __restrict__ nrm4,
                                                   const int* __restrict__ cnt,
                                                   const int* __restrict__ adj,
                                                   float4* __restrict__ SS) {
    int i = blockIdx.x * 256 + threadIdx.x;
    if (i >= N_TOT) return;
    int deg = cnt[i]; if (deg > CAP) deg = CAP;
    const int4* a4 = (const int4*)(adj + (size_t)i * CAP);
    int4 A = a4[0], B = a4[1];
    float4 n0 = nrm4[A.x], n1 = nrm4[A.y], n2 = nrm4[A.z], n3 = nrm4[A.w];
    float4 m0 = nrm4[B.x], m1 = nrm4[B.y], m2 = nrm4[B.z], m3 = nrm4[B.w];
    float sx = ((n0.x + n1.x) + (n2.x + n3.x)) + ((m0.x + m1.x) + (m2.x + m3.x));
    float sy = ((n0.y + n1.y) + (n2.y + n3.y)) + ((m0.y + m1.y) + (m2.y + m3.y));
    float sz = ((n0.z + n1.z) + (n2.z + n3.z)) + ((m0.z + m1.z) + (m2.z + m3.z));
    for (int bq = 8; bq < deg; bq += 8) {
        int4 C = a4[bq / 4], D = a4[bq / 4 + 1];
        float4 p0 = nrm4[C.x], p1 = nrm4[C.y], p2 = nrm4[C.z], p3 = nrm4[C.w];
        float4 q0 = nrm4[D.x], q1 = nrm4[D.y], q2 = nrm4[D.z], q3 = nrm4[D.w];
        sx += ((p0.x + p1.x) + (p2.x + p3.x)) + ((q0.x + q1.x) + (q2.x + q3.x));
        sy += ((p0.y + p1.y) + (p2.y + p3.y)) + ((q0.y + q1.y) + (q2.y + q3.y));
        sz += ((p0.z + p1.z) + (p2.z + p3.z)) + ((q0.z + q1.z) + (q2.z + q3.z));
    }
    float4 out; out.x = sx; out.y = sy; out.z = sz; out.w = (float)deg;
    SS[i] = out;
}

// ---------------- layer 0: analytic h_1 (no gather, no GEMM) ----------------
__global__ __launch_bounds__(1024) void fused1_kernel(const float4* __restrict__ nrm4,
                                                      const float4* __restrict__ SS,
                                                      const float* __restrict__ w0,
                                                      const float* __restrict__ b0,
                                                      const float* __restrict__ w1,
                                                      const float* __restrict__ b1,
                                                      unsigned* __restrict__ hout) { // [N][64]
    __shared__ float wL[2][3][128];
    __shared__ float bL[2][128];
    int tid  = threadIdx.x;
    int w    = tid >> 6;
    int lane = tid & 63;
    int i    = blockIdx.x * 16 + w;

    if (tid < 768) {
        int mm = tid / 384, r = tid - mm * 384;
        (&wL[mm][0][0])[r] = (mm ? w1 : w0)[r];
    } else if (tid < 1024) {
        int t2 = tid - 768;
        if (t2 < 256) bL[t2 >> 7][t2 & 127] = ((t2 >> 7) ? b1 : b0)[t2 & 127];
    }
    float4 self4 = nrm4[i];
    float4 S4 = SS[i];
    float degf = S4.w;
    __syncthreads();

    int c0 = 2 * lane, c1 = 2 * lane + 1;
    float h0 = bL[0][c0] + degf * bL[1][c0]
             + self4.x * wL[0][0][c0] + self4.y * wL[0][1][c0] + self4.z * wL[0][2][c0]
             + S4.x * wL[1][0][c0] + S4.y * wL[1][1][c0] + S4.z * wL[1][2][c0];
    float h1 = bL[0][c1] + degf * bL[1][c1]
             + self4.x * wL[0][0][c1] + self4.y * wL[0][1][c1] + self4.z * wL[0][2][c1]
             + S4.x * wL[1][0][c1] + S4.y * wL[1][1][c1] + S4.z * wL[1][2][c1];
    hout[(size_t)i * 64 + lane] = cvt_pk_bf16(fmaxf(h0, 0.f), fmaxf(h1, 0.f));
}

// ---------------- fused layer (1,2): gather Sum(h) -> [h|S] GEMM + bias head -> h' ----------------
// r12-optimal structure: 512 threads = 8 waves, 16 rows/block; wave w owns nodes 2w, 2w+1.
// 8-wide round 0, A/B tail rounds in parallel to max(degA,degB). deg from SS.w. Regular stores.
template<int LAST>
__global__ __launch_bounds__(512, 8) void fused2_kernel(const unsigned* __restrict__ hin, // [N][64], row -1 = 0
                                                        const float4* __restrict__ nrm4,
                                                        const float4* __restrict__ SS,
                                                        const int* __restrict__ adj,
                                                        const short* __restrict__ Wt,    // [128][KD]
                                                        const float4* __restrict__ hdA,
                                                        const float4* __restrict__ hdB,
                                                        unsigned* __restrict__ hnext,    // !LAST
                                                        const float* __restrict__ verts, // LAST...
                                                        const float* __restrict__ anchor_v,
                                                        const int* __restrict__ part_id,
                                                        const float* __restrict__ w_off,
                                                        const float* __restrict__ b_off,
                                                        float* __restrict__ houtf,
                                                        float* __restrict__ out_verts) {
    __shared__ short tileA[16 * KD];       // 8448 B: [h | S | pad]; LAST: reused as f32 staging
    __shared__ unsigned tileC[16 * 64];    // 4096 B (non-LAST staging)
    __shared__ float headL[16][8];         // n.xyz, deg, Sn.xyz
    __shared__ float woL[131 * 3];         // LAST
    __shared__ float partL[8][16][3];      // LAST

    int tid  = threadIdx.x;
    int w    = tid >> 6;
    int lane = tid & 63;
    int g    = lane >> 4;
    int ln   = lane & 15;
    int row0 = blockIdx.x * 16;
    int rA   = 2 * w, rB = 2 * w + 1;
    int iA   = row0 + rA, iB = row0 + rB;

    if (LAST) {
        for (int t = tid; t < 131 * 3; t += 512) woL[t] = w_off[t];
    }

    // ---- adjacency (A in lanes 0..31, B in lanes 32..63) + self + head data ----
    int node = (lane < 32) ? iA : iB;
    int jv = adj[(size_t)node * CAP + (lane & 31)];
    unsigned selfA = hin[(size_t)iA * 64 + lane];
    unsigned selfB = hin[(size_t)iB * 64 + lane];
    float4 nn = nrm4[node];
    float4 sv = SS[node];
    int degl = (int)sv.w;
    if ((lane & 31) == 0) {
        int r = rA + (lane >> 5);
        headL[r][0] = nn.x; headL[r][1] = nn.y; headL[r][2] = nn.z; headL[r][3] = sv.w;
        headL[r][4] = sv.x; headL[r][5] = sv.y; headL[r][6] = sv.z; headL[r][7] = 0.f;
    }

    // ---- gather round 0: 8+8 unconditional loads in flight ----
    const unsigned* hb = hin + lane;
    unsigned uA[8], uB[8];
    #pragma unroll
    for (int q = 0; q < 8; ++q) {
        int jA = __builtin_amdgcn_readlane(jv, q);
        int jB = __builtin_amdgcn_readlane(jv, 32 + q);
        uA[q] = hb[(ptrdiff_t)jA * 64];
        uB[q] = hb[(ptrdiff_t)jB * 64];
    }
    float sA0 = 0.f, sA1 = 0.f, sB0 = 0.f, sB1 = 0.f;
    #pragma unroll
    for (int q = 0; q < 8; ++q) {
        sA0 += bflo(uA[q]); sA1 += bfhi(uA[q]);
        sB0 += bflo(uB[q]); sB1 += bfhi(uB[q]);
    }
    int degA = __builtin_amdgcn_readlane(degl, 0);
    int degB = __builtin_amdgcn_readlane(degl, 32);
    int degM = (degA > degB) ? degA : degB;
    // ---- extra rounds: A and B issued together (sentinel-padded, branch-free bodies) ----
    for (int bq = 8; bq < degM; bq += 8) {
        unsigned vA[8], vB[8];
        #pragma unroll
        for (int q = 0; q < 8; ++q) {
            int jA = __builtin_amdgcn_readlane(jv, bq + q);
            int jB = __builtin_amdgcn_readlane(jv, 32 + bq + q);
            vA[q] = hb[(ptrdiff_t)jA * 64];
            vB[q] = hb[(ptrdiff_t)jB * 64];
        }
        #pragma unroll
        for (int q = 0; q < 8; ++q) {
            sA0 += bflo(vA[q]); sA1 += bfhi(vA[q]);
            sB0 += bflo(vB[q]); sB1 += bfhi(vB[q]);
        }
    }

    // ---- tileA rows: [self h (64 dw) | S (64 dw) | pad (4 dw)] ----
    unsigned* tA = (unsigned*)tileA;
    tA[rA * 132 + lane]      = selfA;
    tA[rB * 132 + lane]      = selfB;
    tA[rA * 132 + 64 + lane] = cvt_pk_bf16(sA0, sA1);
    tA[rB * 132 + 64 + lane] = cvt_pk_bf16(sB0, sB1);
    if (lane < 4) {
        tA[rA * 132 + 128 + lane] = 0u;
        tA[rB * 132 + 128 + lane] = 0u;
    }
    __syncthreads();

    // ---- MFMA: wave w -> col block w*16, 16 rows, K=256 ----
    int cb = w * 16, c = cb + ln;
    float4 hA = hdA[c], hB = hdB[c];
    bf16x8 bfrag[KSTEPS];
    #pragma unroll
    for (int kk = 0; kk < KSTEPS; ++kk)
        bfrag[kk] = *(const bf16x8*)(Wt + (size_t)c * KD + kk * 32 + g * 8);

    f32x4 acc;
    #pragma unroll
    for (int j = 0; j < 4; ++j) {
        int r = g * 4 + j;
        acc[j] = hA.x + headL[r][3] * hA.y
               + headL[r][0] * hA.z + headL[r][1] * hA.w + headL[r][2] * hB.x
               + headL[r][4] * hB.y + headL[r][5] * hB.z + headL[r][6] * hB.w;
    }
    #pragma unroll
    for (int kk = 0; kk < KSTEPS; ++kk) {
        bf16x8 af = *(const bf16x8*)(tileA + ln * KD + kk * 32 + g * 8);
        acc = __builtin_amdgcn_mfma_f32_16x16x32_bf16(af, bfrag[kk], acc, 0, 0, 0);
    }
    #pragma unroll
    for (int j = 0; j < 4; ++j) acc[j] = fmaxf(acc[j], 0.f);

    if (!LAST) {
        // pack pairs, swizzled store, coalesced writeback (regular stores)
        #pragma unroll
        for (int j = 0; j < 4; ++j) {
            float po = __shfl_xor(acc[j], 1);
            if (!(ln & 1)) {
                unsigned pk = cvt_pk_bf16(acc[j], po);
                int r = g * 4 + j;
                int d = (cb + ln) >> 1;
                tileC[r * 64 + (d ^ ((r & 12) << 1))] = pk;
            }
        }
        __syncthreads();
        int r2 = 2 * w + (lane >> 5);
        int d2 = (lane & 31) * 2;
        int key = (r2 & 12) << 1;
        uint2 v2 = *(const uint2*)&tileC[r2 * 64 + (d2 ^ key)];
        *(uint2*)(hnext + (size_t)(row0 + r2) * 64 + d2) = v2;
    } else {
        // offset head partials (register-only)
        #pragma unroll
        for (int j = 0; j < 4; ++j) {
            int r = g * 4 + j;
            float p0 = acc[j] * woL[c * 3 + 0];
            float p1 = acc[j] * woL[c * 3 + 1];
            float p2 = acc[j] * woL[c * 3 + 2];
            #pragma unroll
            for (int d = 1; d < 16; d <<= 1) {
                p0 += __shfl_xor(p0, d);
                p1 += __shfl_xor(p1, d);
                p2 += __shfl_xor(p2, d);
            }
            if (ln == 0) {
                partL[w][r][0] = p0; partL[w][r][1] = p1; partL[w][r][2] = p2;
            }
        }
        __syncthreads();                       // everyone done reading tileA
        // stage h f32 in LDS (overlay tileA; stride 132 f32 -> 2-way banks)
        float* tCf = (float*)tileA;
        #pragma unroll
        for (int j = 0; j < 4; ++j) {
            int r = g * 4 + j;
            tCf[r * 132 + c] = acc[j];
        }
        __syncthreads();
        // coalesced 512B row stores
        {
            int r = tid >> 5, c4 = (tid & 31) * 4;
            float4 v = *(const float4*)&tCf[r * 132 + c4];
            *(float4*)(houtf + (size_t)(row0 + r) * 128 + c4) = v;
        }
        if (tid < 48) {
            int r = tid / 3, t = tid - r * 3;
            int i = row0 + r;
            float s = 0.f;
            #pragma unroll
            for (int ww = 0; ww < 8; ++ww) s += partL[ww][r][t];
            s += headL[r][0] * woL[128 * 3 + t] + headL[r][1] * woL[129 * 3 + t]
               + headL[r][2] * woL[130 * 3 + t] + b_off[t];
            float dd = tanhf(s);
            int v = i % V_MESH;
            float lim = c_LIM[part_id[v]];
            dd = fminf(fmaxf(dd, -lim), lim);
            out_verts[(size_t)i * 3 + t] =
                verts[(size_t)i * 3 + t] + dd * anchor_v[(size_t)v * 3 + t];
        }
    }
}

extern "C" void kernel_launch(void* const* d_in, const int* in_sizes, int n_in,
                              void* d_out, int out_size, void* d_ws, size_t ws_size,
                              hipStream_t stream) {
    const float* verts    = (const float*)d_in[0];
    const float* normals  = (const float*)d_in[1];
    const float* anchor_v = (const float*)d_in[2];
    const int*   edges    = (const int*)d_in[3];
    const int*   part_id  = (const int*)d_in[4];
    const float* w0_0 = (const float*)d_in[5];
    const float* b0_0 = (const float*)d_in[6];
    const float* w1_0 = (const float*)d_in[7];
    const float* b1_0 = (const float*)d_in[8];
    const float* w0_1 = (const float*)d_in[9];
    const float* b0_1 = (const float*)d_in[10];
    const float* w1_1 = (const float*)d_in[11];
    const float* b1_1 = (const float*)d_in[12];
    const float* w0_2 = (const float*)d_in[13];
    const float* b0_2 = (const float*)d_in[14];
    const float* w1_2 = (const float*)d_in[15];
    const float* b1_2 = (const float*)d_in[16];
    const float* w_off = (const float*)d_in[17];
    const float* b_off = (const float*)d_in[18];

    float* out_verts = (float*)d_out;
    float* houtf = (float*)d_out + (size_t)3 * N_TOT;   // final h (f32)

    char* p = (char*)d_ws;
    unsigned* h1b = (unsigned*)p;  p += (size_t)(N_TOT + 1) * 64 * 4;  // zero row + h1
    unsigned* h2b = (unsigned*)p;  p += (size_t)(N_TOT + 1) * 64 * 4;  // zero row + h2
    int*    cnt  = (int*)p;        p += (size_t)N_TOT * 4;
    int*    adj  = (int*)p;        p += (size_t)N_TOT * CAP * 4;
    short*  Wt1  = (short*)p;      p += 128 * KD * 2;
    short*  Wt2  = (short*)p;      p += 128 * KD * 2;
    float4* hdA1 = (float4*)p;     p += 128 * 16;
    float4* hdB1 = (float4*)p;     p += 128 * 16;
    float4* hdA2 = (float4*)p;     p += 128 * 16;
    float4* hdB2 = (float4*)p;     p += 128 * 16;
    float4* nrm4b = (float4*)p;    p += (size_t)(N_TOT + 1) * 16;      // zero row + nrm4
    float4* SS   = (float4*)p;     p += (size_t)N_TOT * 16;

    unsigned* h1 = h1b + 64;          // row -1 = h1b
    unsigned* h2 = h2b + 64;
    float4* nrm4 = nrm4b + 1;         // row -1 = nrm4b[0]

    // one init kernel replaces 5 memsets + prep + 2 weight-conv dispatches
    init_kernel<<<(N_TOT * CAP / 4 + 255) / 256, 256, 0, stream>>>(
        normals, w0_1, b0_1, w1_1, b1_1, w0_2, b0_2, w1_2, b1_2,
        cnt, (int4*)adj, h1b, h2b, nrm4b, Wt1, hdA1, hdB1, Wt2, hdA2, hdB2);
    fill_adj_kernel<<<(E_TOT + 255) / 256, 256, 0, stream>>>(edges, cnt, adj);
    nsum_kernel<<<(N_TOT + 255) / 256, 256, 0, stream>>>(nrm4, cnt, adj, SS);

    // layer 0: analytic -> h1
    fused1_kernel<<<N_TOT / 16, 1024, 0, stream>>>(nrm4, SS, w0_0, b0_0, w1_0, b1_0, h1);
    // layer 1: gather Sum(h1) -> GEMM -> h2
    fused2_kernel<0><<<N_TOT / 16, 512, 0, stream>>>(h1, nrm4, SS, adj, Wt1, hdA1, hdB1,
                                                     h2, nullptr, nullptr, nullptr, nullptr,
                                                     nullptr, nullptr, nullptr);
    // layer 2 + epilogue: gather Sum(h2) -> GEMM -> h (f32) + verts
    fused2_kernel<1><<<N_TOT / 16, 512, 0, stream>>>(h2, nrm4, SS, adj, Wt2, hdA2, hdB2,
                                                     nullptr, verts, anchor_v, part_id,
                                                     w_off, b_off, houtf, out_verts);
}